// Round 4
// baseline (293.223 us; speedup 1.0000x reference)
//
#include <hip/hip_runtime.h>
#include <math.h>

#define H_ 192
#define W_ 384
#define HW_ 73728

// ---------------------------------------------------------------------------
// K1a: q/k projections.  x [2,64,H,W] -> x1,x2 [2,16,H,W]   (32 accum)
// ---------------------------------------------------------------------------
__global__ __launch_bounds__(256) void k_proj_qk(
    const float* __restrict__ x,
    const float* __restrict__ wq, const float* __restrict__ bq,
    const float* __restrict__ wk, const float* __restrict__ bk,
    float* __restrict__ x1, float* __restrict__ x2)
{
    __shared__ float l[2048 + 32];
    float* lq  = l;
    float* lk  = l + 1024;
    float* lbq = l + 2048;
    float* lbk = l + 2064;
    for (int i = threadIdx.x; i < 1024; i += 256) { lq[i] = wq[i]; lk[i] = wk[i]; }
    if (threadIdx.x < 16) { lbq[threadIdx.x] = bq[threadIdx.x]; lbk[threadIdx.x] = bk[threadIdx.x]; }
    __syncthreads();

    int p = blockIdx.x * 256 + threadIdx.x;
    int n = p / HW_, s = p - n * HW_;

    float aq[16], ak[16];
#pragma unroll
    for (int o = 0; o < 16; o++) { aq[o] = lbq[o]; ak[o] = lbk[o]; }

    const float* xp = x + n * (64 * HW_) + s;
#pragma unroll 4
    for (int c = 0; c < 64; c++) {
        float xv = xp[c * HW_];
#pragma unroll
        for (int o = 0; o < 16; o++) {
            aq[o] = fmaf(lq[o * 64 + c], xv, aq[o]);
            ak[o] = fmaf(lk[o * 64 + c], xv, ak[o]);
        }
    }
#pragma unroll
    for (int o = 0; o < 16; o++) {
        x1[(n * 16 + o) * HW_ + s] = aq[o];
        x2[(n * 16 + o) * HW_ + s] = ak[o];
    }
}

// ---------------------------------------------------------------------------
// K1b: v projection, half the channels per blockIdx.y.  (32 accum)
// x [2,64,H,W] -> x3[half*32 .. half*32+31]
// ---------------------------------------------------------------------------
__global__ __launch_bounds__(256) void k_proj_v(
    const float* __restrict__ x,
    const float* __restrict__ wv, const float* __restrict__ bv,
    float* __restrict__ x3)
{
    __shared__ float l[2048 + 32];
    int half = blockIdx.y;
    for (int i = threadIdx.x; i < 2048; i += 256) l[i] = wv[half * 2048 + i];
    if (threadIdx.x < 32) l[2048 + threadIdx.x] = bv[half * 32 + threadIdx.x];
    __syncthreads();

    int p = blockIdx.x * 256 + threadIdx.x;
    int n = p / HW_, s = p - n * HW_;

    float av[32];
#pragma unroll
    for (int o = 0; o < 32; o++) av[o] = l[2048 + o];

    const float* xp = x + n * (64 * HW_) + s;
#pragma unroll 4
    for (int c = 0; c < 64; c++) {
        float xv = xp[c * HW_];
#pragma unroll
        for (int o = 0; o < 32; o++) av[o] = fmaf(l[o * 64 + c], xv, av[o]);
    }
    float* dst = x3 + (n * 64 + half * 32) * HW_ + s;
#pragma unroll
    for (int o = 0; o < 32; o++) dst[o * HW_] = av[o];
}

// ---------------------------------------------------------------------------
// K2: g-projection.  g [2,128,H,W] -> gg [2,16,H,W]
// ---------------------------------------------------------------------------
__global__ __launch_bounds__(256) void k_proj_g(
    const float* __restrict__ g,
    const float* __restrict__ wg, const float* __restrict__ bg,
    float* __restrict__ gg)
{
    __shared__ float l[2048 + 16];
    for (int i = threadIdx.x; i < 2048; i += 256) l[i] = wg[i];
    if (threadIdx.x < 16) l[2048 + threadIdx.x] = bg[threadIdx.x];
    __syncthreads();

    int p = blockIdx.x * 256 + threadIdx.x;
    int n = p / HW_, s = p - n * HW_;

    float a[16];
#pragma unroll
    for (int o = 0; o < 16; o++) a[o] = l[2048 + o];

    const float* gp = g + n * (128 * HW_) + s;
#pragma unroll 4
    for (int c = 0; c < 128; c++) {
        float gv = gp[c * HW_];
#pragma unroll
        for (int o = 0; o < 16; o++) a[o] = fmaf(l[o * 128 + c], gv, a[o]);
    }
#pragma unroll
    for (int o = 0; o < 16; o++) gg[(n * 16 + o) * HW_ + s] = a[o];
}

// ---------------------------------------------------------------------------
// K3: tap-parallel weight logits. grid (576, 9): blockIdx.y = neighbor tap.
// Each thread computes UNNORMALIZED w1,w2 logits for one (pixel, tap).
// ---------------------------------------------------------------------------
struct WParams {
    const float *x1, *x2, *gg;
    const float *wp;
    const float *bn1g, *bn1b, *bn1m, *bn1v, *w1a;
    const float *bn2g, *bn2b, *bn2m, *bn2v, *w1b, *b1b;
    const float *bn3g, *bn3b, *bn3m, *bn3v, *w2a, *b2a;
    float *w1o, *w2o;   // [n][9][HW] raw logits
};

__global__ __launch_bounds__(256) void k_wtap(WParams P)
{
    __shared__ float ls1[18], lt1[18], lw1a[288];
    __shared__ float ls2[16], lt2[16], lw1b[16];
    __shared__ float ls3[16], lt3[16], lw2a[16];
    __shared__ float lwp[4], lsc[2];

    int t = threadIdx.x;
    if (t < 18) {
        float sc = P.bn1g[t] * rsqrtf(P.bn1v[t] + 1e-5f);
        ls1[t] = sc; lt1[t] = P.bn1b[t] - P.bn1m[t] * sc;
    } else if (t >= 32 && t < 48) {
        int c = t - 32;
        float sc = P.bn2g[c] * rsqrtf(P.bn2v[c] + 1e-5f);
        ls2[c] = sc; lt2[c] = P.bn2b[c] - P.bn2m[c] * sc; lw1b[c] = P.w1b[c];
    } else if (t >= 64 && t < 80) {
        int c = t - 64;
        float sc = P.bn3g[c] * rsqrtf(P.bn3v[c] + 1e-5f);
        ls3[c] = sc; lt3[c] = P.bn3b[c] - P.bn3m[c] * sc; lw2a[c] = P.w2a[c];
    } else if (t >= 96 && t < 100) {
        lwp[t - 96] = P.wp[t - 96];
    } else if (t == 100) {
        lsc[0] = P.b1b[0]; lsc[1] = P.b2a[0];
    }
    for (int i = t; i < 288; i += 256) lw1a[i] = P.w1a[i];
    __syncthreads();

    int k  = blockIdx.y;          // 0..8, uniform
    int ki = k / 3, kj = k - ki * 3;

    int p = blockIdx.x * 256 + t;
    int n = p / HW_, s = p - n * HW_;
    int hi = s / W_, wi = s - hi * W_;

    int hn = hi + ki - 1; hn = (hn < 0) ? -hn : ((hn >= H_) ? 2 * (H_ - 1) - hn : hn);
    int wn = wi + kj - 1; wn = (wn < 0) ? -wn : ((wn >= W_) ? 2 * (W_ - 1) - wn : wn);
    int snk = hn * W_ + wn;
    float dlh = (float)(hi - hn) * (2.0f / (H_ - 1));
    float dlw = (float)(wi - wn) * (2.0f / (W_ - 1));

    const float* x1p = P.x1 + n * (16 * HW_);
    const float* x2p = P.x2 + n * (16 * HW_);
    const float* ggp = P.gg + n * (16 * HW_);

    float h1[16];
#pragma unroll
    for (int o = 0; o < 16; o++) h1[o] = 0.0f;

#pragma unroll
    for (int c = 0; c < 16; c++) {
        float f = x1p[c * HW_ + s] - x2p[c * HW_ + snk];
        f = fmaxf(fmaf(f, ls1[c], lt1[c]), 0.0f);
#pragma unroll
        for (int o = 0; o < 16; o++) h1[o] = fmaf(lw1a[o * 18 + c], f, h1[o]);
    }
#pragma unroll
    for (int pc = 0; pc < 2; pc++) {
        float f = lwp[pc * 2 + 0] * dlw + lwp[pc * 2 + 1] * dlh;
        f = fmaxf(fmaf(f, ls1[16 + pc], lt1[16 + pc]), 0.0f);
#pragma unroll
        for (int o = 0; o < 16; o++) h1[o] = fmaf(lw1a[o * 18 + 16 + pc], f, h1[o]);
    }
    float l1 = lsc[0];
#pragma unroll
    for (int o = 0; o < 16; o++) {
        float v = fmaxf(fmaf(h1[o], ls2[o], lt2[o]), 0.0f);
        l1 = fmaf(lw1b[o], v, l1);
    }

    float l2 = lsc[1];
#pragma unroll
    for (int c = 0; c < 16; c++) {
        float f = ggp[c * HW_ + s] - ggp[c * HW_ + snk];
        f = fmaxf(fmaf(f, ls3[c], lt3[c]), 0.0f);
        l2 = fmaf(lw2a[c], f, l2);
    }

    P.w1o[(n * 9 + k) * HW_ + s] = l1;
    P.w2o[(n * 9 + k) * HW_ + s] = l2;
}

// ---------------------------------------------------------------------------
// K4: 9-tap weighted aggregation; softmax of the 9 raw logits done in-reg.
// grid (576, 4): blockIdx.y = 16-channel slab.
// ---------------------------------------------------------------------------
__global__ __launch_bounds__(256) void k_agg(
    const float* __restrict__ src, const float* __restrict__ wlog,
    float* __restrict__ dst)
{
    int p = blockIdx.x * 256 + threadIdx.x;
    int cb = blockIdx.y;
    int n = p / HW_, s = p - n * HW_;
    int hi = s / W_, wi = s - hi * W_;

    int sn[9];
#pragma unroll
    for (int ki = 0; ki < 3; ki++) {
        int hn = hi + ki - 1; hn = (hn < 0) ? -hn : ((hn >= H_) ? 2 * (H_ - 1) - hn : hn);
#pragma unroll
        for (int kj = 0; kj < 3; kj++) {
            int wn = wi + kj - 1; wn = (wn < 0) ? -wn : ((wn >= W_) ? 2 * (W_ - 1) - wn : wn);
            sn[ki * 3 + kj] = hn * W_ + wn;
        }
    }

    float wv[9];
#pragma unroll
    for (int k = 0; k < 9; k++) wv[k] = wlog[(n * 9 + k) * HW_ + s];
    float m = wv[0];
#pragma unroll
    for (int k = 1; k < 9; k++) m = fmaxf(m, wv[k]);
    float sum = 0.0f;
#pragma unroll
    for (int k = 0; k < 9; k++) { wv[k] = __expf(wv[k] - m); sum += wv[k]; }
    float inv = 1.0f / sum;
#pragma unroll
    for (int k = 0; k < 9; k++) wv[k] *= inv;

#pragma unroll
    for (int ci = 0; ci < 16; ci++) {
        int c = cb * 16 + ci;
        const float* sc_ = src + (n * 64 + c) * HW_;
        float a = 0.0f;
#pragma unroll
        for (int k = 0; k < 9; k++) a = fmaf(wv[k], sc_[sn[k]], a);
        dst[(n * 64 + c) * HW_ + s] = a;
    }
}

// ---------------------------------------------------------------------------
extern "C" void kernel_launch(void* const* d_in, const int* in_sizes, int n_in,
                              void* d_out, int out_size, void* d_ws, size_t ws_size,
                              hipStream_t stream)
{
    const float* x    = (const float*)d_in[0];
    const float* g    = (const float*)d_in[1];
    const float* w_q  = (const float*)d_in[2];
    const float* b_q  = (const float*)d_in[3];
    const float* w_k  = (const float*)d_in[4];
    const float* b_k  = (const float*)d_in[5];
    const float* w_v  = (const float*)d_in[6];
    const float* b_v  = (const float*)d_in[7];
    const float* w_g  = (const float*)d_in[8];
    const float* b_g  = (const float*)d_in[9];
    const float* w_p  = (const float*)d_in[10];
    // d_in[11] = b_p (cancels in center-minus-neighbor subtraction)
    const float* bn1g = (const float*)d_in[12];
    const float* bn1b = (const float*)d_in[13];
    const float* bn1m = (const float*)d_in[14];
    const float* bn1v = (const float*)d_in[15];
    const float* w1a  = (const float*)d_in[16];
    const float* bn2g = (const float*)d_in[17];
    const float* bn2b = (const float*)d_in[18];
    const float* bn2m = (const float*)d_in[19];
    const float* bn2v = (const float*)d_in[20];
    const float* w1b  = (const float*)d_in[21];
    const float* b1b  = (const float*)d_in[22];
    const float* bn3g = (const float*)d_in[23];
    const float* bn3b = (const float*)d_in[24];
    const float* bn3m = (const float*)d_in[25];
    const float* bn3v = (const float*)d_in[26];
    const float* w2a  = (const float*)d_in[27];
    const float* b2a  = (const float*)d_in[28];

    float* ws    = (float*)d_ws;
    float* x1    = ws;                     // 2*16*HW = 2359296 f
    float* x2    = x1 + 2359296;           // 2359296 f
    float* gg    = x2 + 2359296;           // 2359296 f
    float* out1  = gg + 2359296;           // 2*64*HW = 9437184 f
    float* w1log = out1 + 9437184;         // 2*9*HW = 1327104 f
    float* w2log = w1log + 1327104;        // 1327104 f   (total ~76.7 MB)
    float* x3    = (float*)d_out;          // d_out doubles as x3 scratch

    k_proj_qk<<<576, 256, 0, stream>>>(x, w_q, b_q, w_k, b_k, x1, x2);
    k_proj_v<<<dim3(576, 2), 256, 0, stream>>>(x, w_v, b_v, x3);
    k_proj_g<<<576, 256, 0, stream>>>(g, w_g, b_g, gg);

    WParams P;
    P.x1 = x1; P.x2 = x2; P.gg = gg;
    P.wp = w_p;
    P.bn1g = bn1g; P.bn1b = bn1b; P.bn1m = bn1m; P.bn1v = bn1v; P.w1a = w1a;
    P.bn2g = bn2g; P.bn2b = bn2b; P.bn2m = bn2m; P.bn2v = bn2v; P.w1b = w1b; P.b1b = b1b;
    P.bn3g = bn3g; P.bn3b = bn3b; P.bn3m = bn3m; P.bn3v = bn3v; P.w2a = w2a; P.b2a = b2a;
    P.w1o = w1log; P.w2o = w2log;
    k_wtap<<<dim3(576, 9), 256, 0, stream>>>(P);

    k_agg<<<dim3(576, 4), 256, 0, stream>>>(x3, w1log, out1);            // agg1
    k_agg<<<dim3(576, 4), 256, 0, stream>>>(out1, w2log, (float*)d_out); // agg2
}

// Round 5
// 223.557 us; speedup vs baseline: 1.3116x; 1.3116x over previous
//
#include <hip/hip_runtime.h>
#include <math.h>

#define H_ 192
#define W_ 384
#define HW_ 73728

// ---------------------------------------------------------------------------
// K1a: q/k projections.  x [2,64,H,W] -> x1,x2 [2,16,H,W]   (32 accum)
// ---------------------------------------------------------------------------
__global__ __launch_bounds__(256) void k_proj_qk(
    const float* __restrict__ x,
    const float* __restrict__ wq, const float* __restrict__ bq,
    const float* __restrict__ wk, const float* __restrict__ bk,
    float* __restrict__ x1, float* __restrict__ x2)
{
    __shared__ float l[2048 + 32];
    float* lq  = l;
    float* lk  = l + 1024;
    float* lbq = l + 2048;
    float* lbk = l + 2064;
    for (int i = threadIdx.x; i < 1024; i += 256) { lq[i] = wq[i]; lk[i] = wk[i]; }
    if (threadIdx.x < 16) { lbq[threadIdx.x] = bq[threadIdx.x]; lbk[threadIdx.x] = bk[threadIdx.x]; }
    __syncthreads();

    int p = blockIdx.x * 256 + threadIdx.x;
    int n = p / HW_, s = p - n * HW_;

    float aq[16], ak[16];
#pragma unroll
    for (int o = 0; o < 16; o++) { aq[o] = lbq[o]; ak[o] = lbk[o]; }

    const float* xp = x + n * (64 * HW_) + s;
#pragma unroll 4
    for (int c = 0; c < 64; c++) {
        float xv = xp[c * HW_];
#pragma unroll
        for (int o = 0; o < 16; o++) {
            aq[o] = fmaf(lq[o * 64 + c], xv, aq[o]);
            ak[o] = fmaf(lk[o * 64 + c], xv, ak[o]);
        }
    }
#pragma unroll
    for (int o = 0; o < 16; o++) {
        x1[(n * 16 + o) * HW_ + s] = aq[o];
        x2[(n * 16 + o) * HW_ + s] = ak[o];
    }
}

// ---------------------------------------------------------------------------
// K1b: v projection, half the channels per blockIdx.y.  (32 accum)
// ---------------------------------------------------------------------------
__global__ __launch_bounds__(256) void k_proj_v(
    const float* __restrict__ x,
    const float* __restrict__ wv, const float* __restrict__ bv,
    float* __restrict__ x3)
{
    __shared__ float l[2048 + 32];
    int half = blockIdx.y;
    for (int i = threadIdx.x; i < 2048; i += 256) l[i] = wv[half * 2048 + i];
    if (threadIdx.x < 32) l[2048 + threadIdx.x] = bv[half * 32 + threadIdx.x];
    __syncthreads();

    int p = blockIdx.x * 256 + threadIdx.x;
    int n = p / HW_, s = p - n * HW_;

    float av[32];
#pragma unroll
    for (int o = 0; o < 32; o++) av[o] = l[2048 + o];

    const float* xp = x + n * (64 * HW_) + s;
#pragma unroll 4
    for (int c = 0; c < 64; c++) {
        float xv = xp[c * HW_];
#pragma unroll
        for (int o = 0; o < 32; o++) av[o] = fmaf(l[o * 64 + c], xv, av[o]);
    }
    float* dst = x3 + (n * 64 + half * 32) * HW_ + s;
#pragma unroll
    for (int o = 0; o < 32; o++) dst[o * HW_] = av[o];
}

// ---------------------------------------------------------------------------
// K2: g-projection.  g [2,128,H,W] -> gg [2,16,H,W]
// ---------------------------------------------------------------------------
__global__ __launch_bounds__(256) void k_proj_g(
    const float* __restrict__ g,
    const float* __restrict__ wg, const float* __restrict__ bg,
    float* __restrict__ gg)
{
    __shared__ float l[2048 + 16];
    for (int i = threadIdx.x; i < 2048; i += 256) l[i] = wg[i];
    if (threadIdx.x < 16) l[2048 + threadIdx.x] = bg[threadIdx.x];
    __syncthreads();

    int p = blockIdx.x * 256 + threadIdx.x;
    int n = p / HW_, s = p - n * HW_;

    float a[16];
#pragma unroll
    for (int o = 0; o < 16; o++) a[o] = l[2048 + o];

    const float* gp = g + n * (128 * HW_) + s;
#pragma unroll 4
    for (int c = 0; c < 128; c++) {
        float gv = gp[c * HW_];
#pragma unroll
        for (int o = 0; o < 16; o++) a[o] = fmaf(l[o * 128 + c], gv, a[o]);
    }
#pragma unroll
    for (int o = 0; o < 16; o++) gg[(n * 16 + o) * HW_ + s] = a[o];
}

// ---------------------------------------------------------------------------
// K3: tap-parallel weight logits. grid (576, 9): blockIdx.y = neighbor tap.
// ---------------------------------------------------------------------------
struct WParams {
    const float *x1, *x2, *gg;
    const float *wp;
    const float *bn1g, *bn1b, *bn1m, *bn1v, *w1a;
    const float *bn2g, *bn2b, *bn2m, *bn2v, *w1b, *b1b;
    const float *bn3g, *bn3b, *bn3m, *bn3v, *w2a, *b2a;
    float *w1o, *w2o;   // [n][9][HW] raw logits
};

__global__ __launch_bounds__(256) void k_wtap(WParams P)
{
    __shared__ float ls1[18], lt1[18], lw1a[288];
    __shared__ float ls2[16], lt2[16], lw1b[16];
    __shared__ float ls3[16], lt3[16], lw2a[16];
    __shared__ float lwp[4], lsc[2];

    int t = threadIdx.x;
    if (t < 18) {
        float sc = P.bn1g[t] * rsqrtf(P.bn1v[t] + 1e-5f);
        ls1[t] = sc; lt1[t] = P.bn1b[t] - P.bn1m[t] * sc;
    } else if (t >= 32 && t < 48) {
        int c = t - 32;
        float sc = P.bn2g[c] * rsqrtf(P.bn2v[c] + 1e-5f);
        ls2[c] = sc; lt2[c] = P.bn2b[c] - P.bn2m[c] * sc; lw1b[c] = P.w1b[c];
    } else if (t >= 64 && t < 80) {
        int c = t - 64;
        float sc = P.bn3g[c] * rsqrtf(P.bn3v[c] + 1e-5f);
        ls3[c] = sc; lt3[c] = P.bn3b[c] - P.bn3m[c] * sc; lw2a[c] = P.w2a[c];
    } else if (t >= 96 && t < 100) {
        lwp[t - 96] = P.wp[t - 96];
    } else if (t == 100) {
        lsc[0] = P.b1b[0]; lsc[1] = P.b2a[0];
    }
    for (int i = t; i < 288; i += 256) lw1a[i] = P.w1a[i];
    __syncthreads();

    int k  = blockIdx.y;          // 0..8, uniform
    int ki = k / 3, kj = k - ki * 3;

    int p = blockIdx.x * 256 + t;
    int n = p / HW_, s = p - n * HW_;
    int hi = s / W_, wi = s - hi * W_;

    int hn = hi + ki - 1; hn = (hn < 0) ? -hn : ((hn >= H_) ? 2 * (H_ - 1) - hn : hn);
    int wn = wi + kj - 1; wn = (wn < 0) ? -wn : ((wn >= W_) ? 2 * (W_ - 1) - wn : wn);
    int snk = hn * W_ + wn;
    float dlh = (float)(hi - hn) * (2.0f / (H_ - 1));
    float dlw = (float)(wi - wn) * (2.0f / (W_ - 1));

    const float* x1p = P.x1 + n * (16 * HW_);
    const float* x2p = P.x2 + n * (16 * HW_);
    const float* ggp = P.gg + n * (16 * HW_);

    float h1[16];
#pragma unroll
    for (int o = 0; o < 16; o++) h1[o] = 0.0f;

#pragma unroll
    for (int c = 0; c < 16; c++) {
        float f = x1p[c * HW_ + s] - x2p[c * HW_ + snk];
        f = fmaxf(fmaf(f, ls1[c], lt1[c]), 0.0f);
#pragma unroll
        for (int o = 0; o < 16; o++) h1[o] = fmaf(lw1a[o * 18 + c], f, h1[o]);
    }
#pragma unroll
    for (int pc = 0; pc < 2; pc++) {
        float f = lwp[pc * 2 + 0] * dlw + lwp[pc * 2 + 1] * dlh;
        f = fmaxf(fmaf(f, ls1[16 + pc], lt1[16 + pc]), 0.0f);
#pragma unroll
        for (int o = 0; o < 16; o++) h1[o] = fmaf(lw1a[o * 18 + 16 + pc], f, h1[o]);
    }
    float l1 = lsc[0];
#pragma unroll
    for (int o = 0; o < 16; o++) {
        float v = fmaxf(fmaf(h1[o], ls2[o], lt2[o]), 0.0f);
        l1 = fmaf(lw1b[o], v, l1);
    }

    float l2 = lsc[1];
#pragma unroll
    for (int c = 0; c < 16; c++) {
        float f = ggp[c * HW_ + s] - ggp[c * HW_ + snk];
        f = fmaxf(fmaf(f, ls3[c], lt3[c]), 0.0f);
        l2 = fmaf(lw2a[c], f, l2);
    }

    P.w1o[(n * 9 + k) * HW_ + s] = l1;
    P.w2o[(n * 9 + k) * HW_ + s] = l2;
}

// ---------------------------------------------------------------------------
// K4: pixel-vectorized 9-tap aggregation + in-register softmax.
// Each thread: 4 consecutive pixels (one float4 span) x 16 channels.
// grid (144, 4): x = span index over 2*H*W/4 / 256, y = 16-channel slab.
// Horizontal taps reconstructed from 1 aligned float4 + 2 scalars per row;
// reflect padding collapses to address-select (w4==0 -> [1], w4==380 -> [382]).
// ---------------------------------------------------------------------------
__global__ __launch_bounds__(256) void k_agg4(
    const float* __restrict__ src, const float* __restrict__ wlog,
    float* __restrict__ dst)
{
    int tid = blockIdx.x * 256 + threadIdx.x;        // span id, 36864 total
    int cb  = blockIdx.y;
    int n   = tid / (HW_ / 4);
    int r   = tid - n * (HW_ / 4);                   // [0, 18432)
    int hi  = r / (W_ / 4);
    int w4  = (r - hi * (W_ / 4)) * 4;               // 0,4,...,380

    int h0 = (hi == 0) ? 1 : hi - 1;
    int h2 = (hi == H_ - 1) ? H_ - 2 : hi + 1;
    int rows0 = h0 * W_, rows1 = hi * W_, rows2 = h2 * W_;

    int offL = (w4 == 0)   ? 1   : w4 - 1;           // reflected left scalar
    int offR = (w4 == 380) ? 382 : w4 + 4;           // reflected right scalar

    // --- load 9 logit vectors, softmax per component ---
    const float* wl = wlog + n * 9 * HW_ + rows1 + w4;
    float4 wv[9];
#pragma unroll
    for (int k = 0; k < 9; k++) wv[k] = *(const float4*)(wl + k * HW_);
    float4 m = wv[0];
#pragma unroll
    for (int k = 1; k < 9; k++) {
        m.x = fmaxf(m.x, wv[k].x); m.y = fmaxf(m.y, wv[k].y);
        m.z = fmaxf(m.z, wv[k].z); m.w = fmaxf(m.w, wv[k].w);
    }
    float4 sum = make_float4(0.f, 0.f, 0.f, 0.f);
#pragma unroll
    for (int k = 0; k < 9; k++) {
        wv[k].x = __expf(wv[k].x - m.x); sum.x += wv[k].x;
        wv[k].y = __expf(wv[k].y - m.y); sum.y += wv[k].y;
        wv[k].z = __expf(wv[k].z - m.z); sum.z += wv[k].z;
        wv[k].w = __expf(wv[k].w - m.w); sum.w += wv[k].w;
    }
    float4 inv = make_float4(1.f / sum.x, 1.f / sum.y, 1.f / sum.z, 1.f / sum.w);
#pragma unroll
    for (int k = 0; k < 9; k++) {
        wv[k].x *= inv.x; wv[k].y *= inv.y; wv[k].z *= inv.z; wv[k].w *= inv.w;
    }

    const float* srcn = src + n * (64 * HW_);
    float* dstn = dst + n * (64 * HW_) + rows1 + w4;

#pragma unroll 4
    for (int ci = 0; ci < 16; ci++) {
        int c = cb * 16 + ci;
        const float* sp = srcn + c * HW_;
        float4 acc = make_float4(0.f, 0.f, 0.f, 0.f);
        int rr[3] = {rows0, rows1, rows2};
#pragma unroll
        for (int krow = 0; krow < 3; krow++) {
            const float* rowp = sp + rr[krow];
            float4 cv = *(const float4*)(rowp + w4);
            float  lf = rowp[offL];
            float  rt = rowp[offR];
            float4 wL = wv[krow * 3 + 0];
            float4 wC = wv[krow * 3 + 1];
            float4 wR = wv[krow * 3 + 2];
            // left-tap vector  = {lf, cv.x, cv.y, cv.z}
            // center           = cv
            // right-tap vector = {cv.y, cv.z, cv.w, rt}
            acc.x = fmaf(wL.x, lf,   acc.x);
            acc.y = fmaf(wL.y, cv.x, acc.y);
            acc.z = fmaf(wL.z, cv.y, acc.z);
            acc.w = fmaf(wL.w, cv.z, acc.w);
            acc.x = fmaf(wC.x, cv.x, acc.x);
            acc.y = fmaf(wC.y, cv.y, acc.y);
            acc.z = fmaf(wC.z, cv.z, acc.z);
            acc.w = fmaf(wC.w, cv.w, acc.w);
            acc.x = fmaf(wR.x, cv.y, acc.x);
            acc.y = fmaf(wR.y, cv.z, acc.y);
            acc.z = fmaf(wR.z, cv.w, acc.z);
            acc.w = fmaf(wR.w, rt,   acc.w);
        }
        *(float4*)(dstn + c * HW_) = acc;
    }
}

// ---------------------------------------------------------------------------
extern "C" void kernel_launch(void* const* d_in, const int* in_sizes, int n_in,
                              void* d_out, int out_size, void* d_ws, size_t ws_size,
                              hipStream_t stream)
{
    const float* x    = (const float*)d_in[0];
    const float* g    = (const float*)d_in[1];
    const float* w_q  = (const float*)d_in[2];
    const float* b_q  = (const float*)d_in[3];
    const float* w_k  = (const float*)d_in[4];
    const float* b_k  = (const float*)d_in[5];
    const float* w_v  = (const float*)d_in[6];
    const float* b_v  = (const float*)d_in[7];
    const float* w_g  = (const float*)d_in[8];
    const float* b_g  = (const float*)d_in[9];
    const float* w_p  = (const float*)d_in[10];
    // d_in[11] = b_p (cancels in center-minus-neighbor subtraction)
    const float* bn1g = (const float*)d_in[12];
    const float* bn1b = (const float*)d_in[13];
    const float* bn1m = (const float*)d_in[14];
    const float* bn1v = (const float*)d_in[15];
    const float* w1a  = (const float*)d_in[16];
    const float* bn2g = (const float*)d_in[17];
    const float* bn2b = (const float*)d_in[18];
    const float* bn2m = (const float*)d_in[19];
    const float* bn2v = (const float*)d_in[20];
    const float* w1b  = (const float*)d_in[21];
    const float* b1b  = (const float*)d_in[22];
    const float* bn3g = (const float*)d_in[23];
    const float* bn3b = (const float*)d_in[24];
    const float* bn3m = (const float*)d_in[25];
    const float* bn3v = (const float*)d_in[26];
    const float* w2a  = (const float*)d_in[27];
    const float* b2a  = (const float*)d_in[28];

    float* ws    = (float*)d_ws;
    float* x1    = ws;                     // 2*16*HW = 2359296 f
    float* x2    = x1 + 2359296;           // 2359296 f
    float* gg    = x2 + 2359296;           // 2359296 f
    float* out1  = gg + 2359296;           // 2*64*HW = 9437184 f
    float* w1log = out1 + 9437184;         // 2*9*HW = 1327104 f
    float* w2log = w1log + 1327104;        // 1327104 f   (total ~76.7 MB)
    float* x3    = (float*)d_out;          // d_out doubles as x3 scratch

    k_proj_qk<<<576, 256, 0, stream>>>(x, w_q, b_q, w_k, b_k, x1, x2);
    k_proj_v<<<dim3(576, 2), 256, 0, stream>>>(x, w_v, b_v, x3);
    k_proj_g<<<576, 256, 0, stream>>>(g, w_g, b_g, gg);

    WParams P;
    P.x1 = x1; P.x2 = x2; P.gg = gg;
    P.wp = w_p;
    P.bn1g = bn1g; P.bn1b = bn1b; P.bn1m = bn1m; P.bn1v = bn1v; P.w1a = w1a;
    P.bn2g = bn2g; P.bn2b = bn2b; P.bn2m = bn2m; P.bn2v = bn2v; P.w1b = w1b; P.b1b = b1b;
    P.bn3g = bn3g; P.bn3b = bn3b; P.bn3m = bn3m; P.bn3v = bn3v; P.w2a = w2a; P.b2a = b2a;
    P.w1o = w1log; P.w2o = w2log;
    k_wtap<<<dim3(576, 9), 256, 0, stream>>>(P);

    k_agg4<<<dim3(144, 4), 256, 0, stream>>>(x3, w1log, out1);            // agg1
    k_agg4<<<dim3(144, 4), 256, 0, stream>>>(out1, w2log, (float*)d_out); // agg2
}